// Round 1
// baseline (56.326 us; speedup 1.0000x reference)
//
#include <hip/hip_runtime.h>

// scores[q,k] = sum_d tanh(qt[q,d] + kt[k,d]) * v[d]
// qt = query @ Wq^T  [512,256], kt = key @ Wk^T [1024,256], v [256]
// tanh(x) = 1 - 2/(exp(2x)+1)  ->  scores = sum(v) - 2 * sum_d v[d]*rcp(exp2(C*(qt+kt))+1)
// with C = 2*log2(e).

#define TQ 512
#define TK 1024
#define DD 256
#define LOG2E2 2.88539008177792681472f

// ---------------- Projection GEMM (NT): out[i][j] = sum_d X[i][d]*W[j][d] ----------------
// 64x64 tiles, BK=64, 256 threads, 4x4 micro-tile.
__global__ __launch_bounds__(256) void proj_kernel(
    const float* __restrict__ query, const float* __restrict__ key,
    const float* __restrict__ Wq, const float* __restrict__ Wk,
    float* __restrict__ qt, float* __restrict__ kt)
{
    __shared__ float Xs[64][65];
    __shared__ float Ws[64][65];

    int b = blockIdx.x;
    const float* X; const float* W; float* out;
    int rt, ct;
    if (b < 32) {           // query: 8 row tiles x 4 col tiles
        X = query; W = Wq; out = qt; rt = b >> 2; ct = b & 3;
    } else {                // key: 16 row tiles x 4 col tiles
        b -= 32;
        X = key; W = Wk; out = kt; rt = b >> 2; ct = b & 3;
    }
    const int r0 = rt * 64, c0 = ct * 64;
    const int tid = threadIdx.x;
    const int tx = tid & 15, ty = tid >> 4;

    float acc[4][4] = {};

    for (int dc = 0; dc < DD; dc += 64) {
        #pragma unroll
        for (int rep = 0; rep < 4; ++rep) {
            int f = rep * 256 + tid;
            int row = f >> 4, c4 = (f & 15) * 4;
            float4 xv = *(const float4*)&X[(r0 + row) * DD + dc + c4];
            Xs[row][c4 + 0] = xv.x; Xs[row][c4 + 1] = xv.y;
            Xs[row][c4 + 2] = xv.z; Xs[row][c4 + 3] = xv.w;
            float4 wv = *(const float4*)&W[(c0 + row) * DD + dc + c4];
            Ws[row][c4 + 0] = wv.x; Ws[row][c4 + 1] = wv.y;
            Ws[row][c4 + 2] = wv.z; Ws[row][c4 + 3] = wv.w;
        }
        __syncthreads();
        #pragma unroll 8
        for (int d = 0; d < 64; ++d) {
            float xa[4], wb[4];
            #pragma unroll
            for (int i = 0; i < 4; ++i) xa[i] = Xs[ty * 4 + i][d];
            #pragma unroll
            for (int j = 0; j < 4; ++j) wb[j] = Ws[tx * 4 + j][d];
            #pragma unroll
            for (int i = 0; i < 4; ++i)
                #pragma unroll
                for (int j = 0; j < 4; ++j)
                    acc[i][j] = fmaf(xa[i], wb[j], acc[i][j]);
        }
        __syncthreads();
    }

    #pragma unroll
    for (int i = 0; i < 4; ++i) {
        float4 st = make_float4(acc[i][0], acc[i][1], acc[i][2], acc[i][3]);
        *(float4*)&out[(r0 + ty * 4 + i) * DD + c0 + tx * 4] = st;
    }
}

// ---------------- Scores kernel ----------------
// 32(q) x 32(k) tile per block; 256 threads as 16x16; 2x2 micro-tile.
__global__ __launch_bounds__(256) void scores_kernel(
    const float* __restrict__ qt, const float* __restrict__ kt,
    const float* __restrict__ v, float* __restrict__ out)
{
    __shared__ float qs[32][65];
    __shared__ float ks[32][65];
    __shared__ float vs[64];

    const int kb = blockIdx.x;   // 0..31
    const int qb = blockIdx.y;   // 0..15
    const int tid = threadIdx.x;
    const int tx = tid & 15, ty = tid >> 4;

    float acc[2][2] = {};
    float vsum = 0.f;

    for (int dc = 0; dc < DD; dc += 64) {
        #pragma unroll
        for (int rep = 0; rep < 2; ++rep) {
            int f = rep * 256 + tid;
            int row = f >> 4, c4 = (f & 15) * 4;
            float4 qv4 = *(const float4*)&qt[(qb * 32 + row) * DD + dc + c4];
            qs[row][c4 + 0] = qv4.x; qs[row][c4 + 1] = qv4.y;
            qs[row][c4 + 2] = qv4.z; qs[row][c4 + 3] = qv4.w;
            float4 kv4 = *(const float4*)&kt[(kb * 32 + row) * DD + dc + c4];
            ks[row][c4 + 0] = kv4.x; ks[row][c4 + 1] = kv4.y;
            ks[row][c4 + 2] = kv4.z; ks[row][c4 + 3] = kv4.w;
        }
        if (tid < 16) {
            float4 vv = *(const float4*)&v[dc + tid * 4];
            vs[tid * 4 + 0] = vv.x; vs[tid * 4 + 1] = vv.y;
            vs[tid * 4 + 2] = vv.z; vs[tid * 4 + 3] = vv.w;
        }
        __syncthreads();
        #pragma unroll 8
        for (int d = 0; d < 64; ++d) {
            float vd = vs[d];
            vsum += vd;
            float q0 = qs[ty * 2 + 0][d] * LOG2E2;
            float q1 = qs[ty * 2 + 1][d] * LOG2E2;
            float k0 = ks[tx * 2 + 0][d] * LOG2E2;
            float k1 = ks[tx * 2 + 1][d] * LOG2E2;

            float e00 = __builtin_amdgcn_exp2f(q0 + k0);
            float e01 = __builtin_amdgcn_exp2f(q0 + k1);
            float e10 = __builtin_amdgcn_exp2f(q1 + k0);
            float e11 = __builtin_amdgcn_exp2f(q1 + k1);

            float r00 = __builtin_amdgcn_rcpf(e00 + 1.f);
            float r01 = __builtin_amdgcn_rcpf(e01 + 1.f);
            float r10 = __builtin_amdgcn_rcpf(e10 + 1.f);
            float r11 = __builtin_amdgcn_rcpf(e11 + 1.f);

            acc[0][0] = fmaf(vd, r00, acc[0][0]);
            acc[0][1] = fmaf(vd, r01, acc[0][1]);
            acc[1][0] = fmaf(vd, r10, acc[1][0]);
            acc[1][1] = fmaf(vd, r11, acc[1][1]);
        }
        __syncthreads();
    }

    const int orow = qb * 32 + ty * 2;
    const int ocol = kb * 32 + tx * 2;
    #pragma unroll
    for (int i = 0; i < 2; ++i) {
        float2 st;
        st.x = fmaf(-2.f, acc[i][0], vsum);
        st.y = fmaf(-2.f, acc[i][1], vsum);
        *(float2*)&out[(orow + i) * TK + ocol] = st;
    }
}

extern "C" void kernel_launch(void* const* d_in, const int* in_sizes, int n_in,
                              void* d_out, int out_size, void* d_ws, size_t ws_size,
                              hipStream_t stream) {
    const float* query = (const float*)d_in[0];   // [512,256]
    const float* key   = (const float*)d_in[1];   // [1024,256]
    // d_in[2] = value, unused by the reference
    const float* Wq    = (const float*)d_in[3];   // [256,256]
    const float* Wk    = (const float*)d_in[4];   // [256,256]
    const float* vw    = (const float*)d_in[5];   // [1,256]
    float* out = (float*)d_out;                   // [512,1024]

    float* qt = (float*)d_ws;                     // 512*256 f32 = 512KB
    float* kt = qt + TQ * DD;                     // 1024*256 f32 = 1MB

    proj_kernel<<<96, 256, 0, stream>>>(query, key, Wq, Wk, qt, kt);
    dim3 grid(TK / 32, TQ / 32);
    scores_kernel<<<grid, 256, 0, stream>>>(qt, kt, vw, out);
}

// Round 2
// 46.736 us; speedup vs baseline: 1.2052x; 1.2052x over previous
//
#include <hip/hip_runtime.h>

#define DD 256
#define TQ 512
#define TK 1024
#define C2 2.88539008177792681472f   // 2*log2(e)

__device__ __forceinline__ float fexp2(float x){ return __builtin_amdgcn_exp2f(x); }
__device__ __forceinline__ float frcp (float x){ return __builtin_amdgcn_rcpf(x); }

// -------- proj: out[r][c] = sum_d X[r][d] * W[c][d] --------
// tile 32 rows x 16 cols, 1024 threads = 4 K-groups x 256 threads, 2x1 micro.
// grid (16, 48): by<16 -> query tiles, else key tiles.
__global__ __launch_bounds__(1024, 8) void proj_kernel(
    const float* __restrict__ query, const float* __restrict__ key,
    const float* __restrict__ Wq, const float* __restrict__ Wk,
    float* __restrict__ qt, float* __restrict__ kt)
{
    __shared__ float smem[13312];
    float* Xs = smem;            // [256][34]: Xs[d*34 + r], r<32 (transposed)
    float* Ws = smem + 8704;     // [256][18]: Ws[d*18 + c], c<16
    float* red = smem;           // alias, used after sync

    int by = blockIdx.y;
    const float* X; const float* W; float* out;
    if (by < 16) { X = query; W = Wq; out = qt; }
    else { by -= 16; X = key; W = Wk; out = kt; }
    const int r0 = by * 32, c0 = blockIdx.x * 16;
    const int tid = threadIdx.x;

    {
        int f = tid;
        #pragma unroll
        for (int rep = 0; rep < 2; ++rep, f += 1024) {
            int row = f & 31, d4 = (f >> 5) << 2;
            float4 xv = *(const float4*)&X[(r0 + row) * DD + d4];
            Xs[(d4 + 0) * 34 + row] = xv.x;
            Xs[(d4 + 1) * 34 + row] = xv.y;
            Xs[(d4 + 2) * 34 + row] = xv.z;
            Xs[(d4 + 3) * 34 + row] = xv.w;
        }
        int c = tid & 15, d4 = (tid >> 4) << 2;
        float4 wv = *(const float4*)&W[(c0 + c) * DD + d4];
        Ws[(d4 + 0) * 18 + c] = wv.x;
        Ws[(d4 + 1) * 18 + c] = wv.y;
        Ws[(d4 + 2) * 18 + c] = wv.z;
        Ws[(d4 + 3) * 18 + c] = wv.w;
    }
    __syncthreads();

    const int g = tid >> 8, t2 = tid & 255;
    const int cx = t2 & 15, ry = t2 >> 4;     // ry = row-pair index 0..15
    float a0 = 0.f, a1 = 0.f;
    const int dend = g * 64 + 64;
    #pragma unroll 4
    for (int d = g * 64; d < dend; ++d) {
        float2 xv = *(const float2*)&Xs[d * 34 + ry * 2];
        float  wv = Ws[d * 18 + cx];
        a0 = fmaf(xv.x, wv, a0);
        a1 = fmaf(xv.y, wv, a1);
    }
    __syncthreads();
    if (g > 0) {
        red[(g - 1) * 256 + t2]       = a0;
        red[768 + (g - 1) * 256 + t2] = a1;
    }
    __syncthreads();
    if (g == 0) {
        a0 += red[t2] + red[256 + t2] + red[512 + t2];
        a1 += red[768 + t2] + red[1024 + t2] + red[1280 + t2];
        out[(r0 + ry * 2 + 0) * DD + c0 + cx] = a0;
        out[(r0 + ry * 2 + 1) * DD + c0 + cx] = a1;
    }
}

// -------- scores: out[q][k] = vsum - 2 * sum_d v[d] / (2^(qs+ks) + 1) --------
// tile 32 q-rows x 16 k-cols, 1024 threads = 4 d-groups x 256 threads, 2x1 micro.
__global__ __launch_bounds__(1024, 8) void scores_kernel(
    const float* __restrict__ qt, const float* __restrict__ kt,
    const float* __restrict__ v, float* __restrict__ out)
{
    __shared__ float smem[13572];
    float* qs = smem;            // [256][34]: qs[d*34 + r], premultiplied by C2
    float* ks = smem + 8704;     // [256][18]: ks[d*18 + c], premultiplied by C2
    float* vs = smem + 13312;    // [256]
    float* red = smem;           // alias, used after sync; vsum at smem[13568]

    const int qb = blockIdx.y, kb = blockIdx.x;
    const int tid = threadIdx.x;

    {
        int f = tid;
        #pragma unroll
        for (int rep = 0; rep < 2; ++rep, f += 1024) {
            int row = f & 31, d4 = (f >> 5) << 2;
            float4 qv = *(const float4*)&qt[(qb * 32 + row) * DD + d4];
            qs[(d4 + 0) * 34 + row] = qv.x * C2;
            qs[(d4 + 1) * 34 + row] = qv.y * C2;
            qs[(d4 + 2) * 34 + row] = qv.z * C2;
            qs[(d4 + 3) * 34 + row] = qv.w * C2;
        }
        int c = tid & 15, d4 = (tid >> 4) << 2;
        float4 kv = *(const float4*)&kt[(kb * 16 + c) * DD + d4];
        ks[(d4 + 0) * 18 + c] = kv.x * C2;
        ks[(d4 + 1) * 18 + c] = kv.y * C2;
        ks[(d4 + 2) * 18 + c] = kv.z * C2;
        ks[(d4 + 3) * 18 + c] = kv.w * C2;
        if (tid < 64) {
            float4 vv = *(const float4*)&v[tid * 4];
            vs[tid * 4 + 0] = vv.x; vs[tid * 4 + 1] = vv.y;
            vs[tid * 4 + 2] = vv.z; vs[tid * 4 + 3] = vv.w;
            float s = vv.x + vv.y + vv.z + vv.w;
            #pragma unroll
            for (int m = 1; m < 64; m <<= 1) s += __shfl_xor(s, m);
            if (tid == 0) smem[13568] = s;
        }
    }
    __syncthreads();

    const int g = tid >> 8, t2 = tid & 255;
    const int kx = t2 & 15, qy = t2 >> 4;     // qy = q-row-pair 0..15
    float a0 = 0.f, a1 = 0.f;
    const int dend = g * 64 + 64;
    #pragma unroll 4
    for (int d = g * 64; d < dend; ++d) {
        float2 qv = *(const float2*)&qs[d * 34 + qy * 2];
        float  kv = ks[d * 18 + kx];
        float  vd = vs[d];
        float e0 = fexp2(qv.x + kv);
        float e1 = fexp2(qv.y + kv);
        float r0 = frcp(e0 + 1.f);
        float r1 = frcp(e1 + 1.f);
        a0 = fmaf(vd, r0, a0);
        a1 = fmaf(vd, r1, a1);
    }
    float vsum = smem[13568];
    __syncthreads();
    if (g > 0) {
        red[(g - 1) * 256 + t2]       = a0;
        red[768 + (g - 1) * 256 + t2] = a1;
    }
    __syncthreads();
    if (g == 0) {
        a0 += red[t2] + red[256 + t2] + red[512 + t2];
        a1 += red[768 + t2] + red[1024 + t2] + red[1280 + t2];
        const int row = qb * 32 + qy * 2, col = kb * 16 + kx;
        out[row * TK + col]       = fmaf(-2.f, a0, vsum);
        out[(row + 1) * TK + col] = fmaf(-2.f, a1, vsum);
    }
}

extern "C" void kernel_launch(void* const* d_in, const int* in_sizes, int n_in,
                              void* d_out, int out_size, void* d_ws, size_t ws_size,
                              hipStream_t stream) {
    const float* query = (const float*)d_in[0];   // [512,256]
    const float* key   = (const float*)d_in[1];   // [1024,256]
    // d_in[2] = value, unused by the reference
    const float* Wq    = (const float*)d_in[3];   // [256,256]
    const float* Wk    = (const float*)d_in[4];   // [256,256]
    const float* vw    = (const float*)d_in[5];   // [1,256]
    float* out = (float*)d_out;                   // [512,1024]

    float* qt = (float*)d_ws;                     // 512*256 f32
    float* kt = qt + TQ * DD;                     // 1024*256 f32

    proj_kernel<<<dim3(16, 48), 1024, 0, stream>>>(query, key, Wq, Wk, qt, kt);
    scores_kernel<<<dim3(64, 16), 1024, 0, stream>>>(qt, kt, vw, out);
}

// Round 3
// 35.958 us; speedup vs baseline: 1.5665x; 1.2998x over previous
//
#include <hip/hip_runtime.h>

#define DD 256
#define TQ 512
#define TK 1024
#define C2 2.88539008177792681472f   // 2*log2(e)

__device__ __forceinline__ float fexp2(float x){ return __builtin_amdgcn_exp2f(x); }
__device__ __forceinline__ float frcp (float x){ return __builtin_amdgcn_rcpf(x); }

// -------- proj: out[r][c] = exp2( C2 * sum_d X[r][d] * W[c][d] ) --------
// tile 32 rows x 16 cols, 1024 threads = 4 K-groups x 256 threads, 2x1 micro.
// grid (16, 48): by<16 -> query tiles (Eq), else key tiles (Ek).
__global__ __launch_bounds__(1024, 8) void proj_kernel(
    const float* __restrict__ query, const float* __restrict__ key,
    const float* __restrict__ Wq, const float* __restrict__ Wk,
    float* __restrict__ eqo, float* __restrict__ eko)
{
    __shared__ float smem[13312];
    float* Xs = smem;            // [256][34]: Xs[d*34 + r], r<32 (transposed)
    float* Ws = smem + 8704;     // [256][18]: Ws[d*18 + c], c<16
    float* red = smem;           // alias, used after sync

    int by = blockIdx.y;
    const float* X; const float* W; float* out;
    if (by < 16) { X = query; W = Wq; out = eqo; }
    else { by -= 16; X = key; W = Wk; out = eko; }
    const int r0 = by * 32, c0 = blockIdx.x * 16;
    const int tid = threadIdx.x;

    {
        int f = tid;
        #pragma unroll
        for (int rep = 0; rep < 2; ++rep, f += 1024) {
            int row = f & 31, d4 = (f >> 5) << 2;
            float4 xv = *(const float4*)&X[(r0 + row) * DD + d4];
            Xs[(d4 + 0) * 34 + row] = xv.x;
            Xs[(d4 + 1) * 34 + row] = xv.y;
            Xs[(d4 + 2) * 34 + row] = xv.z;
            Xs[(d4 + 3) * 34 + row] = xv.w;
        }
        int c = tid & 15, d4 = (tid >> 4) << 2;
        float4 wv = *(const float4*)&W[(c0 + c) * DD + d4];
        Ws[(d4 + 0) * 18 + c] = wv.x;
        Ws[(d4 + 1) * 18 + c] = wv.y;
        Ws[(d4 + 2) * 18 + c] = wv.z;
        Ws[(d4 + 3) * 18 + c] = wv.w;
    }
    __syncthreads();

    const int g = tid >> 8, t2 = tid & 255;
    const int cx = t2 & 15, ry = t2 >> 4;     // ry = row-pair index 0..15
    float a0 = 0.f, a1 = 0.f;
    const int dend = g * 64 + 64;
    #pragma unroll 4
    for (int d = g * 64; d < dend; ++d) {
        float2 xv = *(const float2*)&Xs[d * 34 + ry * 2];
        float  wv = Ws[d * 18 + cx];
        a0 = fmaf(xv.x, wv, a0);
        a1 = fmaf(xv.y, wv, a1);
    }
    __syncthreads();
    if (g > 0) {
        red[(g - 1) * 256 + t2]       = a0;
        red[768 + (g - 1) * 256 + t2] = a1;
    }
    __syncthreads();
    if (g == 0) {
        a0 += red[t2] + red[256 + t2] + red[512 + t2];
        a1 += red[768 + t2] + red[1024 + t2] + red[1280 + t2];
        out[(r0 + ry * 2 + 0) * DD + c0 + cx] = fexp2(C2 * a0);
        out[(r0 + ry * 2 + 1) * DD + c0 + cx] = fexp2(C2 * a1);
    }
}

// -------- scores: out[q][k] = vsum - 2 * sum_d v[d] / (Eq[q][d]*Ek[k][d] + 1) --------
// tile 32 q x 32 k, 1024 threads = 4 d-groups x 256 threads, 2x2 micro.
__global__ __launch_bounds__(1024, 8) void scores_kernel(
    const float* __restrict__ eqg, const float* __restrict__ ekg,
    const float* __restrict__ v, float* __restrict__ out)
{
    __shared__ float smem[17668];
    float* eq = smem;            // [256][34]: eq[d*34 + r], r<32
    float* ek = smem + 8704;     // [256][34]: ek[d*34 + c], c<32
    float* vs = smem + 17408;    // [256]
    // vsum at smem[17664]; reduction buffer aliases smem[0..3071]

    const int qb = blockIdx.y, kb = blockIdx.x;
    const int tid = threadIdx.x;

    {
        int f = tid;
        #pragma unroll
        for (int rep = 0; rep < 2; ++rep, f += 1024) {
            int row = f & 31, d4 = (f >> 5) << 2;
            float4 qv = *(const float4*)&eqg[(qb * 32 + row) * DD + d4];
            eq[(d4 + 0) * 34 + row] = qv.x;
            eq[(d4 + 1) * 34 + row] = qv.y;
            eq[(d4 + 2) * 34 + row] = qv.z;
            eq[(d4 + 3) * 34 + row] = qv.w;
            float4 kv = *(const float4*)&ekg[(kb * 32 + row) * DD + d4];
            ek[(d4 + 0) * 34 + row] = kv.x;
            ek[(d4 + 1) * 34 + row] = kv.y;
            ek[(d4 + 2) * 34 + row] = kv.z;
            ek[(d4 + 3) * 34 + row] = kv.w;
        }
        if (tid < 64) {
            float4 vv = *(const float4*)&v[tid * 4];
            vs[tid * 4 + 0] = vv.x; vs[tid * 4 + 1] = vv.y;
            vs[tid * 4 + 2] = vv.z; vs[tid * 4 + 3] = vv.w;
            float s = vv.x + vv.y + vv.z + vv.w;
            #pragma unroll
            for (int m = 1; m < 64; m <<= 1) s += __shfl_xor(s, m);
            if (tid == 0) smem[17664] = s;
        }
    }
    __syncthreads();

    const int g = tid >> 8, t2 = tid & 255;
    const int kx2 = (t2 & 15) * 2, qy2 = (t2 >> 4) * 2;
    float a00 = 0.f, a01 = 0.f, a10 = 0.f, a11 = 0.f;
    const int dend = g * 64 + 64;
    #pragma unroll 4
    for (int d = g * 64; d < dend; ++d) {
        float2 q2 = *(const float2*)&eq[d * 34 + qy2];
        float2 k2 = *(const float2*)&ek[d * 34 + kx2];
        float  vd = vs[d];
        float r00 = frcp(fmaf(q2.x, k2.x, 1.f));
        float r01 = frcp(fmaf(q2.x, k2.y, 1.f));
        float r10 = frcp(fmaf(q2.y, k2.x, 1.f));
        float r11 = frcp(fmaf(q2.y, k2.y, 1.f));
        a00 = fmaf(vd, r00, a00);
        a01 = fmaf(vd, r01, a01);
        a10 = fmaf(vd, r10, a10);
        a11 = fmaf(vd, r11, a11);
    }
    float vsum = smem[17664];
    __syncthreads();
    if (g > 0) {
        float4 st = make_float4(a00, a01, a10, a11);
        *(float4*)&smem[((g - 1) * 256 + t2) * 4] = st;
    }
    __syncthreads();
    if (g == 0) {
        #pragma unroll
        for (int i = 0; i < 3; ++i) {
            float4 p = *(float4*)&smem[(i * 256 + t2) * 4];
            a00 += p.x; a01 += p.y; a10 += p.z; a11 += p.w;
        }
        const int row = qb * 32 + qy2, col = kb * 32 + kx2;
        float2 s0 = make_float2(fmaf(-2.f, a00, vsum), fmaf(-2.f, a01, vsum));
        float2 s1 = make_float2(fmaf(-2.f, a10, vsum), fmaf(-2.f, a11, vsum));
        *(float2*)&out[row * TK + col]       = s0;
        *(float2*)&out[(row + 1) * TK + col] = s1;
    }
}

extern "C" void kernel_launch(void* const* d_in, const int* in_sizes, int n_in,
                              void* d_out, int out_size, void* d_ws, size_t ws_size,
                              hipStream_t stream) {
    const float* query = (const float*)d_in[0];   // [512,256]
    const float* key   = (const float*)d_in[1];   // [1024,256]
    // d_in[2] = value, unused by the reference
    const float* Wq    = (const float*)d_in[3];   // [256,256]
    const float* Wk    = (const float*)d_in[4];   // [256,256]
    const float* vw    = (const float*)d_in[5];   // [1,256]
    float* out = (float*)d_out;                   // [512,1024]

    float* eq = (float*)d_ws;                     // 512*256 f32
    float* ek = eq + TQ * DD;                     // 1024*256 f32

    proj_kernel<<<dim3(16, 48), 1024, 0, stream>>>(query, key, Wq, Wk, eq, ek);
    scores_kernel<<<dim3(TK / 32, TQ / 32), 1024, 0, stream>>>(eq, ek, vw, out);
}